// Round 12
// baseline (282.380 us; speedup 1.0000x reference)
//
#include <hip/hip_runtime.h>

typedef _Float16 f16x8 __attribute__((ext_vector_type(8)));
typedef unsigned short u16x8 __attribute__((ext_vector_type(8)));
typedef float f32x4  __attribute__((ext_vector_type(4)));
typedef unsigned short u16;

#define T_SEQ 2048
#define C_DIM 1024
#define NH 16
#define HS 64
#define S_SETS 1023
#define S_PAD 1024
#define SCALE 0.125f     // 1/sqrt(64), pre-folded into q16
#define NEG_BIG -1e30f
#define M_INIT -1e20f    // running-max floor: exp(NEG_BIG - M_INIT) == 0 exactly

#define GLB(p) ((const __attribute__((address_space(1))) void*)(p))
#define LDS(p) ((__attribute__((address_space(3))) void*)(p))

__device__ __forceinline__ u16 f2h(float f) {
    _Float16 h = (_Float16)f;
    return __builtin_bit_cast(unsigned short, h);
}
__device__ __forceinline__ float h2f(u16 u) {
    _Float16 h = __builtin_bit_cast(_Float16, u);
    return (float)h;
}
__device__ __forceinline__ f32x4 mfmah(f16x8 a, f16x8 b, f32x4 c) {
    return __builtin_amdgcn_mfma_f32_16x16x32_f16(a, b, c, 0, 0, 0);
}

// -------- Kernel P: build sort-by-r permutation ------------------------------
// rank = lvl + sum_L' min(2048/L', floor(r/L')); r32[rank] = r.
__global__ __launch_bounds__(256) void build_perm(int* __restrict__ rankArr,
                                                  int* __restrict__ r32) {
    int s = blockIdx.x * 256 + threadIdx.x;
    if (s >= 1024) return;
    if (s == 1023) { r32[1023] = 0x7fffffff; return; }
    int e = S_SETS - s;
    int l = __clz(e) - 22;             // level: L = 4<<l
    int base = 1024 - (1024 >> l);
    int i = s - base;
    int L = 4 << l;
    int r = (i + 1) * L - 1;
    int rank = l;
    #pragma unroll
    for (int j = 0; j < 10; ++j) {
        int cnt = r >> (j + 2);
        int cap = 512 >> j;
        rank += (cnt < cap) ? cnt : cap;
    }
    rankArr[s] = rank;
    r32[rank] = r;
}

// -------- Kernel 0: fp32 -> fp16 ---------------------------------------------
__global__ __launch_bounds__(256) void conv_f16(const float* __restrict__ in,
                                                u16* __restrict__ out, int n4) {
    int i = blockIdx.x * 256 + threadIdx.x;
    if (i >= n4) return;
    float4 f = ((const float4*)in)[i];
    ushort4 o;
    o.x = f2h(f.x); o.y = f2h(f.y); o.z = f2h(f.z); o.w = f2h(f.w);
    ((ushort4*)out)[i] = o;
}

// -------- Kernel 1: qkv = x @ W_attn^T, fp16 MFMA, 128x128 tile --------------
__global__ __launch_bounds__(256) void gemm_qkv16(const u16* __restrict__ x16,
                                                  const u16* __restrict__ wa16,
                                                  u16* __restrict__ q16,
                                                  u16* __restrict__ k16,
                                                  u16* __restrict__ v16) {
    __shared__ u16 As[128 * 32];
    __shared__ u16 Bs[128 * 32];
    int tid = threadIdx.x, wv = tid >> 6, lane = tid & 63;
    int lm = lane & 15, quad = lane >> 4;
    int mt = blockIdx.x / 24, nt = blockIdx.x % 24;
    int wm = wv >> 1, wn = wv & 1;
    int m_off = wm * 64, n_off = wn * 64;

    const u16* gsrc;
    u16* ldst;
    int half = wv & 1;
    if (wv < 2) { gsrc = x16  + (size_t)(mt * 128 + half * 64) * C_DIM; ldst = As + half * 64 * 32; }
    else        { gsrc = wa16 + (size_t)(nt * 128 + half * 64) * C_DIM; ldst = Bs + half * 64 * 32; }
    int srow = lane >> 2, scol = (lane & 3) * 8;

    f32x4 acc[4][4];
    #pragma unroll
    for (int i = 0; i < 4; ++i)
        #pragma unroll
        for (int j = 0; j < 4; ++j) acc[i][j] = (f32x4){0.f, 0.f, 0.f, 0.f};

    for (int k0 = 0; k0 < C_DIM; k0 += 32) {
        __syncthreads();
        #pragma unroll
        for (int i = 0; i < 4; ++i) {
            int row = i * 16 + srow;
            __builtin_amdgcn_global_load_lds(
                GLB(gsrc + (size_t)row * C_DIM + k0 + scol),
                LDS(ldst + i * 512), 16, 0, 0);
        }
        __syncthreads();
        f16x8 af[4], bf[4];
        #pragma unroll
        for (int i = 0; i < 4; ++i) {
            af[i] = *(const f16x8*)(As + (m_off + i * 16 + lm) * 32 + quad * 8);
            bf[i] = *(const f16x8*)(Bs + (n_off + i * 16 + lm) * 32 + quad * 8);
        }
        #pragma unroll
        for (int mi = 0; mi < 4; ++mi)
            #pragma unroll
            for (int ni = 0; ni < 4; ++ni)
                acc[mi][ni] = mfmah(af[mi], bf[ni], acc[mi][ni]);
    }

    #pragma unroll
    for (int mi = 0; mi < 4; ++mi)
        #pragma unroll
        for (int ni = 0; ni < 4; ++ni) {
            int n = nt * 128 + n_off + ni * 16 + lm;
            int which = n >> 10, h = (n >> 6) & 15, d = n & 63;
            #pragma unroll
            for (int reg = 0; reg < 4; ++reg) {
                int m = mt * 128 + m_off + mi * 16 + quad * 4 + reg;
                int b_ = m >> 11, t = m & 2047;
                size_t oi = (((size_t)(b_ * NH + h)) * T_SEQ + t) * HS + d;
                float val = acc[mi][ni][reg];
                if (which == 0)      q16[oi] = f2h(val * SCALE);
                else if (which == 1) k16[oi] = f2h(val);
                else                 v16[oi] = f2h(val);
            }
        }
}

// -------- Kernel 2: set sums -> fp16, scattered to rank order ----------------
__global__ __launch_bounds__(256) void set_sums(const u16* __restrict__ k16,
                                                const u16* __restrict__ v16,
                                                const int* __restrict__ rankArr,
                                                u16* __restrict__ K16,
                                                u16* __restrict__ VT16) {
    int bh  = blockIdx.x;
    int src = blockIdx.y >> 2;
    int dc  = blockIdx.y & 3;
    int tid = threadIdx.x;
    __shared__ float lv0[512 * 16];
    __shared__ float lv1[256 * 16];
    const u16* sp = src ? v16 : k16;
    u16* op = src ? VT16 : K16;
    int dbase = dc * 16;
    for (int idx = tid; idx < 512 * 16; idx += 256) {
        int sg = idx >> 4, dd = idx & 15, d = dbase + dd;
        const u16* p = sp + ((size_t)bh * T_SEQ + sg * 4) * HS + d;
        float s = h2f(p[0]) + h2f(p[HS]) + h2f(p[2 * HS]) + h2f(p[3 * HS]);
        lv0[sg * 16 + dd] = s;
        int rnk = rankArr[sg];
        size_t o = src ? ((size_t)bh * HS + d) * S_PAD + rnk
                       : ((size_t)bh * S_PAD + rnk) * HS + d;
        op[o] = f2h(s);
    }
    __syncthreads();
    int nsets = 256, offset = 512, lvl = 1;
    while (nsets >= 1) {
        float* sbuf = (lvl & 1) ? lv0 : lv1;
        float* dbuf = (lvl & 1) ? lv1 : lv0;
        for (int idx = tid; idx < nsets * 16; idx += 256) {
            int i = idx >> 4, dd = idx & 15, d = dbase + dd;
            float s = sbuf[(2 * i) * 16 + dd] + sbuf[(2 * i + 1) * 16 + dd];
            dbuf[i * 16 + dd] = s;
            int rnk = rankArr[offset + i];
            size_t o = src ? ((size_t)bh * HS + d) * S_PAD + rnk
                           : ((size_t)bh * S_PAD + rnk) * HS + d;
            op[o] = f2h(s);
        }
        __syncthreads();
        offset += nsets; nsets >>= 1; lvl++;
    }
    if (tid < 16) {     // zero the pad rank 1023
        int d = dbase + tid;
        if (src == 0) K16[((size_t)bh * S_PAD + 1023) * HS + d] = 0;
        else          VT16[((size_t)bh * HS + d) * S_PAD + 1023] = 0;
    }
}

// -------- Kernel 3: flash attention over rank-sorted sets --------------------
// Block = 64 contiguous queries (heavy-first: t0 = 1984 - 64*bx). Valid sets
// form a prefix; block stages only nch = ceil(nval(tmax)/128) chunks.
__global__ __launch_bounds__(256) void attn_flash16(const u16* __restrict__ q16,
                                                    const u16* __restrict__ k16,
                                                    const u16* __restrict__ v16,
                                                    const u16* __restrict__ K16,
                                                    const u16* __restrict__ VT16,
                                                    const int* __restrict__ r32g,
                                                    u16* __restrict__ att16) {
    int bh = blockIdx.y;
    int t0 = 1984 - 64 * blockIdx.x;
    int tid = threadIdx.x, wv = tid >> 6, lane = tid & 63;
    int lm = lane & 15, quad = lane >> 4;
    int t0w = t0 + wv * 16;
    int twmax = t0w + 15;

    __shared__ u16 Ks[128 * 64];     // K chunk fp16, XOR-swizzled (16KB)
    __shared__ u16 Pbuf[4][16 * 136];// per-wave P fp16 (A-layout rows)
    __shared__ float ptl[4][16];     // per-wave tail logits

    // block-uniform chunk count: nval(t) = sum_j (t+1)>>j, j=2..11
    int nch;
    {
        int tp1 = t0 + 64;
        int nval = 0;
        #pragma unroll
        for (int j = 2; j <= 11; ++j) nval += tp1 >> j;
        nch = (nval + 127) >> 7;
    }

    const u16* qg = q16 + ((size_t)bh * T_SEQ + t0w + lm) * HS;
    f16x8 a0 = *(const f16x8*)(qg + quad * 8);
    f16x8 a1 = *(const f16x8*)(qg + 32 + quad * 8);

    f32x4 O[4];
    #pragma unroll
    for (int i = 0; i < 4; ++i) O[i] = (f32x4){0.f, 0.f, 0.f, 0.f};
    f32x4 mrun = (f32x4){M_INIT, M_INIT, M_INIT, M_INIT};
    f32x4 lrun = (f32x4){0.f, 0.f, 0.f, 0.f};

    u16* Pw = &Pbuf[wv][0];
    const u16* vb = VT16 + (size_t)bh * HS * S_PAD;
    bool done = false;

    for (int c = 0; c < nch; ++c) {
        int s0 = c * 128;
        __syncthreads();
        {   // cooperative K-chunk staging (XOR swizzle)
            int row = tid >> 1, gb = (tid & 1) * 4, rx = row & 7;
            const u16* gk = K16 + ((size_t)bh * S_PAD + s0 + row) * HS;
            u16* dst = Ks + row * 64;
            #pragma unroll
            for (int uu = 0; uu < 4; ++uu) {
                int g = gb + uu;
                *(u16x8*)(dst + ((g ^ rx) << 3)) = *(const u16x8*)(gk + g * 8);
            }
        }
        __syncthreads();
        if (done) continue;

        // QK^T: 8 s-tiles; sorted order => flags form a prefix mask
        unsigned flags = 0;
        f32x4 lt[8];
        #pragma unroll
        for (int st = 0; st < 8; ++st) {
            int s = s0 + st * 16 + lm;
            int r = r32g[s];
            unsigned long long bal = __ballot(r <= twmax);
            if (bal) {
                flags |= 1u << st;
                int sl = st * 16 + lm, sx = sl & 7;
                f16x8 b0 = *(const f16x8*)(Ks + sl * 64 + ((quad ^ sx) << 3));
                f16x8 b1 = *(const f16x8*)(Ks + sl * 64 + (((4 + quad) ^ sx) << 3));
                f32x4 a = (f32x4){0.f, 0.f, 0.f, 0.f};
                a = mfmah(a0, b0, a);
                a = mfmah(a1, b1, a);
                #pragma unroll
                for (int reg = 0; reg < 4; ++reg) {
                    int t = t0w + quad * 4 + reg;
                    lt[st][reg] = (r <= t) ? a[reg] : NEG_BIG;
                }
            }
        }
        if (!flags) { done = true; continue; }

        // online softmax update (unguarded exp: mrun floor makes exp exact 0)
        f32x4 mc = (f32x4){NEG_BIG, NEG_BIG, NEG_BIG, NEG_BIG};
        #pragma unroll
        for (int st = 0; st < 8; ++st)
            if ((flags >> st) & 1u)
                #pragma unroll
                for (int reg = 0; reg < 4; ++reg) mc[reg] = fmaxf(mc[reg], lt[st][reg]);
        #pragma unroll
        for (int off = 1; off < 16; off <<= 1)
            #pragma unroll
            for (int reg = 0; reg < 4; ++reg)
                mc[reg] = fmaxf(mc[reg], __shfl_xor(mc[reg], off));
        f32x4 mnew, alpha, rs = (f32x4){0.f, 0.f, 0.f, 0.f};
        #pragma unroll
        for (int reg = 0; reg < 4; ++reg) {
            mnew[reg] = fmaxf(mrun[reg], mc[reg]);
            alpha[reg] = __expf(mrun[reg] - mnew[reg]);
        }
        #pragma unroll
        for (int st = 0; st < 8; ++st) {
            if ((flags >> st) & 1u) {
                #pragma unroll
                for (int reg = 0; reg < 4; ++reg) {
                    float p = __expf(lt[st][reg] - mnew[reg]);
                    rs[reg] += p;
                    Pw[(quad * 4 + reg) * 136 + st * 16 + lm] = f2h(p);
                }
            } else {
                #pragma unroll
                for (int reg = 0; reg < 4; ++reg)
                    Pw[(quad * 4 + reg) * 136 + st * 16 + lm] = 0;
            }
        }
        #pragma unroll
        for (int off = 1; off < 16; off <<= 1)
            #pragma unroll
            for (int reg = 0; reg < 4; ++reg) rs[reg] += __shfl_xor(rs[reg], off);
        #pragma unroll
        for (int reg = 0; reg < 4; ++reg) {
            lrun[reg] = lrun[reg] * alpha[reg] + rs[reg];
            mrun[reg] = mnew[reg];
        }
        #pragma unroll
        for (int dt = 0; dt < 4; ++dt)
            #pragma unroll
            for (int reg = 0; reg < 4; ++reg) O[dt][reg] *= alpha[reg];

        // P @ V chunk
        #pragma unroll
        for (int kc = 0; kc < 4; ++kc) {
            if (!((flags >> (2 * kc)) & 3u)) continue;
            f16x8 afr = *(const f16x8*)(Pw + lm * 136 + kc * 32 + quad * 8);
            #pragma unroll
            for (int dt = 0; dt < 4; ++dt) {
                size_t vo = (size_t)(dt * 16 + lm) * S_PAD + s0 + kc * 32 + quad * 8;
                f16x8 bv = *(const f16x8*)(vb + vo);
                O[dt] = mfmah(afr, bv, O[dt]);
            }
        }
        if (flags != 0xFFu) done = true;   // boundary inside chunk => rest empty
    }

    // tail logit per row
    {
        int rqr = lane >> 2, prt = lane & 3;
        int tt = t0w + rqr;
        int lenr = (tt & 3) + 1;
        float ktv[16];
        #pragma unroll
        for (int dd = 0; dd < 16; ++dd) ktv[dd] = 0.f;
        for (int j = 0; j < lenr; ++j) {
            const u16* kp = k16 + ((size_t)bh * T_SEQ + tt - j) * HS + prt * 16;
            #pragma unroll
            for (int dd = 0; dd < 16; ++dd) ktv[dd] += h2f(kp[dd]);
        }
        const u16* tq = q16 + ((size_t)bh * T_SEQ + tt) * HS + prt * 16;
        float tlp = 0.f;
        #pragma unroll
        for (int dd = 0; dd < 16; ++dd) tlp += h2f(tq[dd]) * ktv[dd];
        tlp += __shfl_xor(tlp, 1);
        tlp += __shfl_xor(tlp, 2);
        if (prt == 0) ptl[wv][rqr] = tlp;
    }
    __syncthreads();

    // epilogue: merge tail, normalize, store fp16
    int b_ = bh >> 4, h_ = bh & 15;
    #pragma unroll
    for (int reg = 0; reg < 4; ++reg) {
        int row = quad * 4 + reg;
        int t = t0w + row;
        float tl = ptl[wv][row];
        float mfin = fmaxf(mrun[reg], tl);
        float pt = __expf(tl - mfin);
        float af = __expf(mrun[reg] - mfin);
        float inv = 1.0f / (lrun[reg] * af + pt);
        int len = (t & 3) + 1;
        #pragma unroll
        for (int dt = 0; dt < 4; ++dt) {
            int d = dt * 16 + lm;
            const u16* vp = v16 + ((size_t)bh * T_SEQ + t) * HS + d;
            float vt = 0.f;
            for (int j = 0; j < len; ++j) vt += h2f(vp[-(j * HS)]);
            float val = (O[dt][reg] * af + pt * vt) * inv;
            att16[((size_t)(b_ * T_SEQ + t)) * C_DIM + h_ * HS + d] = f2h(val);
        }
    }
}

// -------- Kernel 4: out = attout @ W_proj^T, fp16 MFMA, fp32 out -------------
__global__ __launch_bounds__(256) void gemm_proj16(const u16* __restrict__ a_,
                                                   const u16* __restrict__ w,
                                                   float* __restrict__ out) {
    __shared__ u16 As[128 * 32];
    __shared__ u16 Bs[128 * 32];
    int tid = threadIdx.x, wv = tid >> 6, lane = tid & 63;
    int lm = lane & 15, quad = lane >> 4;
    int mt = blockIdx.x >> 3, nt = blockIdx.x & 7;
    int wm = wv >> 1, wn = wv & 1;
    int m_off = wm * 64, n_off = wn * 64;

    const u16* gsrc;
    u16* ldst;
    int half = wv & 1;
    if (wv < 2) { gsrc = a_ + (size_t)(mt * 128 + half * 64) * C_DIM; ldst = As + half * 64 * 32; }
    else        { gsrc = w  + (size_t)(nt * 128 + half * 64) * C_DIM; ldst = Bs + half * 64 * 32; }
    int srow = lane >> 2, scol = (lane & 3) * 8;

    f32x4 acc[4][4];
    #pragma unroll
    for (int i = 0; i < 4; ++i)
        #pragma unroll
        for (int j = 0; j < 4; ++j) acc[i][j] = (f32x4){0.f, 0.f, 0.f, 0.f};

    for (int k0 = 0; k0 < C_DIM; k0 += 32) {
        __syncthreads();
        #pragma unroll
        for (int i = 0; i < 4; ++i) {
            int row = i * 16 + srow;
            __builtin_amdgcn_global_load_lds(
                GLB(gsrc + (size_t)row * C_DIM + k0 + scol),
                LDS(ldst + i * 512), 16, 0, 0);
        }
        __syncthreads();
        f16x8 af[4], bf[4];
        #pragma unroll
        for (int i = 0; i < 4; ++i) {
            af[i] = *(const f16x8*)(As + (m_off + i * 16 + lm) * 32 + quad * 8);
            bf[i] = *(const f16x8*)(Bs + (n_off + i * 16 + lm) * 32 + quad * 8);
        }
        #pragma unroll
        for (int mi = 0; mi < 4; ++mi)
            #pragma unroll
            for (int ni = 0; ni < 4; ++ni)
                acc[mi][ni] = mfmah(af[mi], bf[ni], acc[mi][ni]);
    }

    #pragma unroll
    for (int mi = 0; mi < 4; ++mi)
        #pragma unroll
        for (int ni = 0; ni < 4; ++ni) {
            int n = nt * 128 + n_off + ni * 16 + lm;
            #pragma unroll
            for (int reg = 0; reg < 4; ++reg) {
                int m = mt * 128 + m_off + mi * 16 + quad * 4 + reg;
                out[(size_t)m * C_DIM + n] = acc[mi][ni][reg];
            }
        }
}

extern "C" void kernel_launch(void* const* d_in, const int* in_sizes, int n_in,
                              void* d_out, int out_size, void* d_ws, size_t ws_size,
                              hipStream_t stream) {
    const float* x     = (const float*)d_in[0];
    const float* Wattn = (const float*)d_in[1];
    const float* Wproj = (const float*)d_in[2];
    float* out = (float*)d_out;
    char* ws = (char*)d_ws;
    // workspace layout (58.7 MB + 8KB tables)
    u16* x16   = (u16*)(ws + 0);           //  8,388,608
    u16* wa16  = (u16*)(ws + 8388608);     //  6,291,456
    u16* wp16  = (u16*)(ws + 14680064);    //  2,097,152
    u16* q16   = (u16*)(ws + 16777216);    //  8,388,608 (pre-scaled by 1/8)
    u16* k16   = (u16*)(ws + 25165824);    //  8,388,608
    u16* v16   = (u16*)(ws + 33554432);    //  8,388,608
    u16* K16   = (u16*)(ws + 41943040);    //  4,194,304 (rank-sorted rows)
    u16* VT16  = (u16*)(ws + 46137344);    //  4,194,304 (rank-sorted cols)
    u16* att16 = (u16*)(ws + 50331648);    //  8,388,608
    int* rankA = (int*)(ws + 58720256);    //  4,096
    int* r32   = (int*)(ws + 58724352);    //  4,096 (end 58,728,448)

    hipLaunchKernelGGL(build_perm, dim3(4), dim3(256), 0, stream, rankA, r32);
    hipLaunchKernelGGL(conv_f16, dim3(4096), dim3(256), 0, stream, x, x16, 1048576);
    hipLaunchKernelGGL(conv_f16, dim3(3072), dim3(256), 0, stream, Wattn, wa16, 786432);
    hipLaunchKernelGGL(conv_f16, dim3(1024), dim3(256), 0, stream, Wproj, wp16, 262144);
    hipLaunchKernelGGL(gemm_qkv16, dim3(768), dim3(256), 0, stream, x16, wa16, q16, k16, v16);
    hipLaunchKernelGGL(set_sums, dim3(32, 8), dim3(256), 0, stream, k16, v16, rankA, K16, VT16);
    hipLaunchKernelGGL(attn_flash16, dim3(32, 32), dim3(256), 0, stream,
                       q16, k16, v16, K16, VT16, r32, att16);
    hipLaunchKernelGGL(gemm_proj16, dim3(256), dim3(256), 0, stream, att16, wp16, out);
}